// Round 2
// baseline (403.872 us; speedup 1.0000x reference)
//
#include <hip/hip_runtime.h>

// Problem constants (match reference)
#define BB 64
#define MM 2048
#define DD 512
#define CHUNK 64                 // rows of M handled per block
#define SPLITS (MM / CHUNK)      // 32 partials per batch row

// Kernel 1: per (batch b, chunk c) block, find max squared-distance row.
// 256 threads = 4 waves. Within a wave: 4 groups of 16 lanes; each group
// owns one row per pass (4 rows in flight), each lane accumulates 32
// elements (8 x float4). One 4-step xor-butterfly reduces all 4 rows at
// once. This keeps 8 independent float4 loads in flight per lane-pass and
// cuts shuffle ops ~6x vs a per-row 64-lane reduction.
__global__ __launch_bounds__(256) void dist_argmax_kernel(
    const float* __restrict__ inputs,   // [B, D]
    const float* __restrict__ buffer,   // [B, M, D]
    float* __restrict__ ws_d,           // [B, SPLITS]
    int*   __restrict__ ws_i)           // [B, SPLITS]
{
    const int b     = blockIdx.x;
    const int chunk = blockIdx.y;
    const int tid   = threadIdx.x;
    const int lane  = tid & 63;
    const int wave  = tid >> 6;
    const int g     = lane >> 4;   // group 0..3 (row within pass)
    const int j     = lane & 15;   // lane within group

    // Query slice: lane covers float4 positions j, j+16, ..., j+112
    const float4* q4 = (const float4*)(inputs + (size_t)b * DD);
    float4 q[8];
    #pragma unroll
    for (int k = 0; k < 8; k++) q[k] = q4[j + k * 16];

    const float* base =
        buffer + (size_t)b * MM * DD + (size_t)chunk * CHUNK * DD;

    float best_d = -1.0f;
    int   best_i = 0;

    #pragma unroll
    for (int p = 0; p < 4; p++) {
        const int r = wave * 16 + p * 4 + g;            // 0..63, increasing in p
        const float4* row4 = (const float4*)(base + (size_t)r * DD);
        float s = 0.0f;
        #pragma unroll
        for (int k = 0; k < 8; k++) {
            float4 v = row4[j + k * 16];
            float dx;
            dx = v.x - q[k].x; s = fmaf(dx, dx, s);
            dx = v.y - q[k].y; s = fmaf(dx, dx, s);
            dx = v.z - q[k].z; s = fmaf(dx, dx, s);
            dx = v.w - q[k].w; s = fmaf(dx, dx, s);
        }
        // butterfly sum within each 16-lane group (all 4 rows at once)
        #pragma unroll
        for (int off = 1; off < 16; off <<= 1)
            s += __shfl_xor(s, off, 64);
        // every lane in the group now has row r's total; visit order is
        // increasing r, strict > keeps the first occurrence
        if (s > best_d) { best_d = s; best_i = r; }
    }

    // cross-group argmax within the wave (xor 16, 32); tie -> lower index
    #pragma unroll
    for (int off = 16; off < 64; off <<= 1) {
        float od = __shfl_xor(best_d, off, 64);
        int   oi = __shfl_xor(best_i, off, 64);
        if (od > best_d || (od == best_d && oi < best_i)) {
            best_d = od; best_i = oi;
        }
    }

    __shared__ float sd[4];
    __shared__ int   si[4];
    if (lane == 0) { sd[wave] = best_d; si[wave] = best_i; }
    __syncthreads();
    if (tid == 0) {
        float bd = sd[0]; int bi = si[0];
        #pragma unroll
        for (int w = 1; w < 4; w++) {
            if (sd[w] > bd || (sd[w] == bd && si[w] < bi)) { bd = sd[w]; bi = si[w]; }
        }
        ws_d[b * SPLITS + chunk] = bd;
        ws_i[b * SPLITS + chunk] = chunk * CHUNK + bi;
    }
}

// Kernel 2: reduce the 32 partials per batch row, gather the winning row.
__global__ __launch_bounds__(128) void gather_kernel(
    const float* __restrict__ ws_d,
    const int*   __restrict__ ws_i,
    const float* __restrict__ buffer,
    float*       __restrict__ out)
{
    const int b   = blockIdx.x;
    const int tid = threadIdx.x;
    __shared__ int s_idx;

    if (tid < 64) {
        float d = (tid < SPLITS) ? ws_d[b * SPLITS + tid] : -1.0f;
        int   i = (tid < SPLITS) ? ws_i[b * SPLITS + tid] : 0x7fffffff;
        #pragma unroll
        for (int off = 32; off > 0; off >>= 1) {
            float od = __shfl_down(d, off, 64);
            int   oi = __shfl_down(i, off, 64);
            if (od > d || (od == d && oi < i)) { d = od; i = oi; }
        }
        if (tid == 0) s_idx = i;
    }
    __syncthreads();

    const int idx = s_idx;
    const float4* src = (const float4*)(buffer + ((size_t)b * MM + idx) * DD);
    float4*       dst = (float4*)(out + (size_t)b * DD);
    dst[tid] = src[tid];   // D/4 = 128 float4s, 128 threads
}

extern "C" void kernel_launch(void* const* d_in, const int* in_sizes, int n_in,
                              void* d_out, int out_size, void* d_ws, size_t ws_size,
                              hipStream_t stream) {
    const float* inputs = (const float*)d_in[0];   // [B, D]
    const float* buffer = (const float*)d_in[1];   // [B, M, D]
    float* out  = (float*)d_out;                   // [B, D]
    float* ws_d = (float*)d_ws;                    // [B, SPLITS]
    int*   ws_i = (int*)(ws_d + BB * SPLITS);      // [B, SPLITS]

    dim3 grid(BB, SPLITS);
    dist_argmax_kernel<<<grid, 256, 0, stream>>>(inputs, buffer, ws_d, ws_i);
    gather_kernel<<<BB, 128, 0, stream>>>(ws_d, ws_i, buffer, out);
}